// Round 1
// baseline (37960.873 us; speedup 1.0000x reference)
//
#include <hip/hip_runtime.h>

// SNN-MNIST forward + STDP, MI355X persistent cooperative kernel.
// Round 5: neuron-slice ownership restructure. 100 blocks x 1024 threads,
// each block owns 4 output neurons: W-slice + syn/mem/post live in LDS,
// STDP reads tr/img straight from global (no LDS staging redundancy),
// ONE grid barrier per step (was 2). Cross-block data: tr ring (sc1),
// active lists ring (sc1), t-tagged win atomics, per-step flag.

#define T_STEPS 200
#define BATCH   256
#define INQ     784
#define NOUT    400
#define GRID    100
#define NTHR    1024
#define IMSZ    200704            // 256*784

// ws layout (32-bit words)
#define OFF_TR    0               // tr ring  [2][256][784] f32
#define OFF_LST   401408          // lists    [3][256][84]  i32
#define OFF_LCNT  465920          // counts   [3][256]      u32
#define OFF_WIN   466688          // win ring [2][256][16]  u32 (64B padded)
#define OFF_FLAGS 474880          // flags    [256]         u32 (per-t any-spike)
#define OFF_BAR   475136          // barrier  [2048]        u32
#define WS_FLOATS 477184

typedef unsigned long long ull;

// ---- agent-coherent (sc1) helpers: bypass per-XCD L2 ----
__device__ __forceinline__ float ld_coh(const float* p) {
  return __hip_atomic_load(p, __ATOMIC_RELAXED, __HIP_MEMORY_SCOPE_AGENT);
}
__device__ __forceinline__ float2 ld_coh2(const float* p) {
  union { ull u; float2 f; } c;
  c.u = __hip_atomic_load((const ull*)p, __ATOMIC_RELAXED, __HIP_MEMORY_SCOPE_AGENT);
  return c.f;
}
__device__ __forceinline__ ull ld_coh64(const void* p) {
  return __hip_atomic_load((const ull*)p, __ATOMIC_RELAXED, __HIP_MEMORY_SCOPE_AGENT);
}
__device__ __forceinline__ unsigned ld_cohu(const unsigned* p) {
  return __hip_atomic_load(p, __ATOMIC_RELAXED, __HIP_MEMORY_SCOPE_AGENT);
}
__device__ __forceinline__ void st_coh2(float* p, float2 v) {
  union { ull u; float2 f; } c; c.f = v;
  __hip_atomic_store((ull*)p, c.u, __ATOMIC_RELAXED, __HIP_MEMORY_SCOPE_AGENT);
}
__device__ __forceinline__ void st_cohi(int* p, int v) {
  __hip_atomic_store(p, v, __ATOMIC_RELAXED, __HIP_MEMORY_SCOPE_AGENT);
}
__device__ __forceinline__ void st_cohu(unsigned* p, unsigned v) {
  __hip_atomic_store(p, v, __ATOMIC_RELAXED, __HIP_MEMORY_SCOPE_AGENT);
}

// Hierarchical fence-free grid barrier: 100 blocks = 25 groups x 4.
// Monotonic counters (no reset). __syncthreads() drains vmcnt pre-arrival.
__device__ __forceinline__ void gbar(unsigned* bar, unsigned k, int blk) {
  __syncthreads();
  if (threadIdx.x == 0) {
    const int g = blk >> 2;
    unsigned* garr = bar + g * 64;
    unsigned* ggen = garr + 32;
    unsigned* rarr = bar + 25 * 64;
    unsigned* rgen = rarr + 32;
    unsigned a = __hip_atomic_fetch_add(garr, 1u, __ATOMIC_RELAXED, __HIP_MEMORY_SCOPE_AGENT);
    if (a + 1u == k * 4u) {
      unsigned r = __hip_atomic_fetch_add(rarr, 1u, __ATOMIC_RELAXED, __HIP_MEMORY_SCOPE_AGENT);
      if (r + 1u == k * 25u) {
        __hip_atomic_store(rgen, k, __ATOMIC_RELAXED, __HIP_MEMORY_SCOPE_AGENT);
      } else {
        while (__hip_atomic_load(rgen, __ATOMIC_RELAXED, __HIP_MEMORY_SCOPE_AGENT) < k)
          __builtin_amdgcn_s_sleep(1);
      }
      __hip_atomic_store(ggen, k, __ATOMIC_RELAXED, __HIP_MEMORY_SCOPE_AGENT);
    } else {
      while (__hip_atomic_load(ggen, __ATOMIC_RELAXED, __HIP_MEMORY_SCOPE_AGENT) < k)
        __builtin_amdgcn_s_sleep(1);
    }
  }
  __syncthreads();
}

// ---- STDP streaming batch (4 b-rows, 3 main i-slots + optional tail) ----
struct Batch {
  float t0[4], t1[4], t2[4];      // tr  at i0, i0+64, i0+128
  float u0[4], u1[4], u2[4];      // img at i0, i0+64, i0+128
  float tt[4], ti[4];             // tail (i = it), taker waves only
};

__device__ __forceinline__ void sload(Batch& P, const float* trb, const float* imgt,
                                      int b2s, int i0, bool taker, int it) {
#pragma unroll
  for (int q = 0; q < 4; ++q) {
    const size_t ro = (size_t)(b2s + q) * INQ;
    P.t0[q] = ld_coh(trb + ro + i0);
    P.t1[q] = ld_coh(trb + ro + i0 + 64);
    P.t2[q] = ld_coh(trb + ro + i0 + 128);
    P.u0[q] = imgt[ro + i0];
    P.u1[q] = imgt[ro + i0 + 64];
    P.u2[q] = imgt[ro + i0 + 128];
    if (taker) { P.tt[q] = ld_coh(trb + ro + it); P.ti[q] = imgt[ro + it]; }
  }
}

__device__ __forceinline__ void scomp(const Batch& P, float (*spo)[8],
                                      int b2s, bool taker, int ntl,
                                      float4& aA, float4& aB, float4& aC, float& aT) {
#pragma unroll
  for (int q = 0; q < 4; ++q) {
    const int b2 = b2s + q;
    const float4 ap = *(const float4*)&spo[b2][0];   // 1e-3*spk broadcast
    const float4 am = *(const float4*)&spo[b2][4];   // 1e-3*post broadcast
    aA.x = fmaf(P.t0[q], ap.x, fmaf(P.u0[q], -am.x, aA.x));
    aA.y = fmaf(P.t0[q], ap.y, fmaf(P.u0[q], -am.y, aA.y));
    aA.z = fmaf(P.t0[q], ap.z, fmaf(P.u0[q], -am.z, aA.z));
    aA.w = fmaf(P.t0[q], ap.w, fmaf(P.u0[q], -am.w, aA.w));
    aB.x = fmaf(P.t1[q], ap.x, fmaf(P.u1[q], -am.x, aB.x));
    aB.y = fmaf(P.t1[q], ap.y, fmaf(P.u1[q], -am.y, aB.y));
    aB.z = fmaf(P.t1[q], ap.z, fmaf(P.u1[q], -am.z, aB.z));
    aB.w = fmaf(P.t1[q], ap.w, fmaf(P.u1[q], -am.w, aB.w));
    aC.x = fmaf(P.t2[q], ap.x, fmaf(P.u2[q], -am.x, aC.x));
    aC.y = fmaf(P.t2[q], ap.y, fmaf(P.u2[q], -am.y, aC.y));
    aC.z = fmaf(P.t2[q], ap.z, fmaf(P.u2[q], -am.z, aC.z));
    aC.w = fmaf(P.t2[q], ap.w, fmaf(P.u2[q], -am.w, aC.w));
    if (taker) {
      const float tp = spo[b2][ntl], tm = spo[b2][4 + ntl];
      aT = fmaf(P.tt[q], tp, fmaf(P.ti[q], -tm, aT));
    }
  }
}

__global__ void __launch_bounds__(NTHR) snn_kernel(
    const float* __restrict__ img,   // [200][256][784]
    const float* __restrict__ Win,   // [400][784]
    float* __restrict__ out,         // mem_rec | spk_rec | W_final
    float* ws)
{
  float*    trw  = ws + OFF_TR;
  int*      lst  = (int*)(ws + OFF_LST);
  unsigned* lcnt = (unsigned*)(ws + OFF_LCNT);
  unsigned* winw = (unsigned*)(ws + OFF_WIN);
  unsigned* flg  = (unsigned*)(ws + OFF_FLAGS);
  unsigned* bar  = (unsigned*)(ws + OFF_BAR);

  float* mem_rec = out;
  float* spk_rec = out + (size_t)T_STEPS * BATCH * NOUT;
  float* Wout    = out + (size_t)2 * T_STEPS * BATCH * NOUT;

  const int tid = threadIdx.x, blk = blockIdx.x;
  const int wv = tid >> 6, ln = tid & 63;
  const int n0 = blk * 4;                                // owned neurons n0..n0+3
  const int rs = (blk * BATCH) / GRID;                   // owned tr/list rows
  const int re = ((blk + 1) * BATCH) / GRID;

  // STDP geometry: 4 groups x 4 waves; group g handles b in [64g,64g+64).
  // wave (g,p): i-slots p*192+ln (+64,+128); one wave per group (p==g) also
  // takes the 16-wide tail i=768..783 (lane = (i-768)*4 + n).
  const int sg = wv >> 2, sp_ = wv & 3;
  const int i0 = sp_ * 192 + ln;
  const bool taker = (sp_ == sg);
  const int it = 768 + (ln >> 2), ntl = ln & 3;
  const int b2base = sg * 64;

  __shared__ float s_W[785][4];          // [i][n] owned W slice (+zero pad row)
  __shared__ float s_spo[BATCH][8];      // [b][1e-3*spk x4 | 1e-3*post x4]
  __shared__ float s_state[12][BATCH];   // rows: syn0-3, mem0-3, post0-3

  // ordered active-index compaction for img[tt] rows [rs,re) -> ring slot tt%3
  auto build_lists = [&](int tt, int wbase) {
    if (wv < wbase || wv >= wbase + (re - rs)) return;
    const int r = rs + (wv - wbase);
    const float* imrow = img + (size_t)tt * IMSZ + (size_t)r * INQ;
    int* drow = lst + ((size_t)(tt % 3) * BATCH + r) * 84;
    int base = 0;
    for (int c = 0; c < 13; ++c) {
      int i = c * 64 + ln;
      bool act = (i < INQ) && (imrow[i] != 0.0f);
      ull m = __ballot(act);
      if (act) {
        int p = base + (int)__popcll(m & ((1ull << ln) - 1ull));
        if (p < 80) st_cohi(drow + p, i);
      }
      base += (int)__popcll(m);
    }
    if (base > 80) base = 80;
    int c4 = (base + 3) & ~3;
    if (ln < c4 - base) st_cohi(drow + base + ln, 784);   // sentinel pad (W row 784 = 0)
    if (ln == 0) st_cohu(lcnt + (size_t)(tt % 3) * BATCH + r, (unsigned)c4);
  };

  // ---- prologue: W slice -> LDS, zero state, lists[0] ----
  for (int n = 0; n < 4; ++n)
    for (int i = tid; i < INQ; i += NTHR)
      s_W[i][n] = Win[(size_t)(n0 + n) * INQ + i];
  if (tid < 4) s_W[784][tid] = 0.0f;
  for (int e = tid; e < 12 * BATCH; e += NTHR) ((float*)s_state)[e] = 0.0f;
  build_lists(0, 0);
  unsigned bt = 1;
  gbar(bar, bt, blk);

  for (int t = 0; t < T_STEPS; ++t) {
    __syncthreads();   // B(t-1) LDS writes -> A(t) reads

    // ================= A: neuron update (1 barrier-epoch producer) ==========
    if (tid < BATCH) {
      const int b = tid;
      float sy0 = s_state[0][b], sy1 = s_state[1][b], sy2 = s_state[2][b], sy3 = s_state[3][b];
      float me0 = s_state[4][b], me1 = s_state[5][b], me2 = s_state[6][b], me3 = s_state[7][b];
      float po0 = s_state[8][b], po1 = s_state[9][b], po2 = s_state[10][b], po3 = s_state[11][b];
      const int slot = t % 3;
      const int* lrow = lst + ((size_t)slot * BATCH + b) * 84;
      int cnt = (int)ld_cohu(lcnt + (size_t)slot * BATCH + b);
      int e[48];
#pragma unroll
      for (int h = 0; h < 24; ++h) {            // 48 entries up-front, in flight
        ull v = ld_coh64((const ull*)lrow + h);
        e[2 * h] = (int)(unsigned)v; e[2 * h + 1] = (int)(v >> 32);
      }
      float c0 = 0.f, c1 = 0.f, c2 = 0.f, c3 = 0.f;
#pragma unroll
      for (int j = 0; j < 48; j += 4) {         // ascending-i exact order
        if (j < cnt) {
          float4 w0 = *(const float4*)&s_W[e[j + 0]][0];
          float4 w1 = *(const float4*)&s_W[e[j + 1]][0];
          float4 w2 = *(const float4*)&s_W[e[j + 2]][0];
          float4 w3 = *(const float4*)&s_W[e[j + 3]][0];
          c0 += w0.x; c1 += w0.y; c2 += w0.z; c3 += w0.w;
          c0 += w1.x; c1 += w1.y; c2 += w1.z; c3 += w1.w;
          c0 += w2.x; c1 += w2.y; c2 += w2.z; c3 += w2.w;
          c0 += w3.x; c1 += w3.y; c2 += w3.z; c3 += w3.w;
        }
      }
      for (int j = 48; j < cnt; j += 2) {       // rare tail (cnt>48)
        ull v = ld_coh64((const ull*)lrow + (j >> 1));
        float4 w0 = *(const float4*)&s_W[(int)(unsigned)v][0];
        float4 w1 = *(const float4*)&s_W[(int)(v >> 32)][0];
        c0 += w0.x; c1 += w0.y; c2 += w0.z; c3 += w0.w;
        c0 += w1.x; c1 += w1.y; c2 += w1.z; c3 += w1.w;
      }
      sy0 = fmaf(0.9f, sy0, c0); sy1 = fmaf(0.9f, sy1, c1);
      sy2 = fmaf(0.9f, sy2, c2); sy3 = fmaf(0.9f, sy3, c3);
      float r0 = (me0 > 1.0f) ? 1.0f : 0.0f;
      float r1 = (me1 > 1.0f) ? 1.0f : 0.0f;
      float r2 = (me2 > 1.0f) ? 1.0f : 0.0f;
      float r3 = (me3 > 1.0f) ? 1.0f : 0.0f;
      me0 = fmaf(0.8f, me0, sy0) - r0; me1 = fmaf(0.8f, me1, sy1) - r1;
      me2 = fmaf(0.8f, me2, sy2) - r2; me3 = fmaf(0.8f, me3, sy3) - r3;
      float k0 = (me0 > 1.0f) ? 1.0f : 0.0f;
      float k1 = (me1 > 1.0f) ? 1.0f : 0.0f;
      float k2 = (me2 > 1.0f) ? 1.0f : 0.0f;
      float k3 = (me3 > 1.0f) ? 1.0f : 0.0f;
      const size_t ridx = ((size_t)t * BATCH + b) * NOUT + n0;
      *(float4*)(mem_rec + ridx) = make_float4(me0, me1, me2, me3);
      *(float4*)(spk_rec + ridx) = make_float4(k0, k1, k2, k3);
      po0 = fmaf(0.9f, po0, k0); po1 = fmaf(0.9f, po1, k1);
      po2 = fmaf(0.9f, po2, k2); po3 = fmaf(0.9f, po3, k3);
      s_state[0][b] = sy0; s_state[1][b] = sy1; s_state[2][b] = sy2; s_state[3][b] = sy3;
      s_state[4][b] = me0; s_state[5][b] = me1; s_state[6][b] = me2; s_state[7][b] = me3;
      s_state[8][b] = po0; s_state[9][b] = po1; s_state[10][b] = po2; s_state[11][b] = po3;
      *(float4*)&s_spo[b][0] = make_float4(1e-3f * k0, 1e-3f * k1, 1e-3f * k2, 1e-3f * k3);
      *(float4*)&s_spo[b][4] = make_float4(1e-3f * po0, 1e-3f * po1, 1e-3f * po2, 1e-3f * po3);
      bool spiked = (k0 != 0.f) || (k1 != 0.f) || (k2 != 0.f) || (k3 != 0.f);
      if (spiked) {
        int nm = (k0 != 0.f) ? n0 : (k1 != 0.f) ? n0 + 1 : (k2 != 0.f) ? n0 + 2 : n0 + 3;
        unsigned val = ((unsigned)(t + 1) << 9) | (unsigned)(401 - nm);  // t-tagged, no reset
        __hip_atomic_fetch_max(winw + (size_t)(t & 1) * BATCH * 16 + (size_t)b * 16, val,
                               __ATOMIC_RELAXED, __HIP_MEMORY_SCOPE_AGENT);
      }
      ull mb = __ballot(spiked);
      if (spiked && (mb & ((1ull << ln) - 1ull)) == 0ull)
        __hip_atomic_fetch_or(flg + t, 1u, __ATOMIC_RELAXED, __HIP_MEMORY_SCOPE_AGENT);
    } else if (wv >= 4 && wv < 8) {
      // tr[t] = 0.9*tr[t-1] + img[t-1] on owned rows (tr[0] = memset zeros)
      if (t > 0) {
        const int k = tid - 256;
        const float* trP = trw + (size_t)((t - 1) & 1) * IMSZ;
        float*       trN = trw + (size_t)(t & 1) * IMSZ;
        const float* imP = img + (size_t)(t - 1) * IMSZ;
        for (int ee = rs * INQ + k * 2; ee < re * INQ; ee += 512) {
          float2 o = ld_coh2(trP + ee);
          float2 iv = *(const float2*)(imP + ee);
          st_coh2(trN + ee, make_float2(fmaf(0.9f, o.x, iv.x), fmaf(0.9f, o.y, iv.y)));
        }
      }
    }
    if (t + 1 < T_STEPS) build_lists(t + 1, 8);   // waves 8..10

    ++bt; gbar(bar, bt, blk);

    // ================= B: STDP into LDS-W + lateral inhibition ==============
    unsigned vw = 0u, vf = 0u;
    if (tid < BATCH) {            // issue early; consumed after STDP loop
      vw = ld_cohu(winw + (size_t)(t & 1) * BATCH * 16 + (size_t)tid * 16);
      vf = ld_cohu(flg + t);
    }
    const float* trb  = trw + (size_t)(t & 1) * IMSZ;
    const float* imgt = img + (size_t)t * IMSZ;
    float4 aA = make_float4(0.f, 0.f, 0.f, 0.f), aB = aA, aC = aA;
    float aT = 0.f;
    Batch PA, PB;
    sload(PA, trb, imgt, b2base + 0, i0, taker, it);
    for (int bb = 0; bb < 64; bb += 8) {          // b ascending within group
      sload(PB, trb, imgt, b2base + bb + 4, i0, taker, it);
      scomp(PA, s_spo, b2base + bb, taker, ntl, aA, aB, aC, aT);
      if (bb + 8 < 64) sload(PA, trb, imgt, b2base + bb + 8, i0, taker, it);
      scomp(PB, s_spo, b2base + bb + 4, taker, ntl, aA, aB, aC, aT);
    }
    if (tid < BATCH && vf != 0u) {                // winner-take-all inhibition
      const int b = tid;
      const int wb = ((vw >> 9) == (unsigned)(t + 1)) ? (401 - (int)(vw & 511u)) : 0;
      if (n0 + 0 != wb) s_state[0][b] -= 0.1f;
      if (n0 + 1 != wb) s_state[1][b] -= 0.1f;
      if (n0 + 2 != wb) s_state[2][b] -= 0.1f;
      if (n0 + 3 != wb) s_state[3][b] -= 0.1f;
    }
    // ordered combine: W += d(g0); += d(g1); += d(g2); += d(g3) then clamp
    for (int gg = 0; gg < 4; ++gg) {
      __syncthreads();
      if (sg == gg) {
        const bool last = (gg == 3);
        float4 w;
        w = *(const float4*)&s_W[i0][0];
        w.x += aA.x; w.y += aA.y; w.z += aA.z; w.w += aA.w;
        if (last) {
          w.x = fminf(fmaxf(w.x, 0.f), 1.f); w.y = fminf(fmaxf(w.y, 0.f), 1.f);
          w.z = fminf(fmaxf(w.z, 0.f), 1.f); w.w = fminf(fmaxf(w.w, 0.f), 1.f);
        }
        *(float4*)&s_W[i0][0] = w;
        w = *(const float4*)&s_W[i0 + 64][0];
        w.x += aB.x; w.y += aB.y; w.z += aB.z; w.w += aB.w;
        if (last) {
          w.x = fminf(fmaxf(w.x, 0.f), 1.f); w.y = fminf(fmaxf(w.y, 0.f), 1.f);
          w.z = fminf(fmaxf(w.z, 0.f), 1.f); w.w = fminf(fmaxf(w.w, 0.f), 1.f);
        }
        *(float4*)&s_W[i0 + 64][0] = w;
        w = *(const float4*)&s_W[i0 + 128][0];
        w.x += aC.x; w.y += aC.y; w.z += aC.z; w.w += aC.w;
        if (last) {
          w.x = fminf(fmaxf(w.x, 0.f), 1.f); w.y = fminf(fmaxf(w.y, 0.f), 1.f);
          w.z = fminf(fmaxf(w.z, 0.f), 1.f); w.w = fminf(fmaxf(w.w, 0.f), 1.f);
        }
        *(float4*)&s_W[i0 + 128][0] = w;
        if (taker) {
          float wt = s_W[it][ntl] + aT;
          if (last) wt = fminf(fmaxf(wt, 0.f), 1.f);
          s_W[it][ntl] = wt;
        }
      }
    }
  }

  // ---- epilogue: W_final[n][i] from LDS ----
  __syncthreads();
  for (int e2 = tid; e2 < 4 * INQ; e2 += NTHR) {
    int n = e2 / INQ, i = e2 % INQ;
    Wout[(size_t)(n0 + n) * INQ + i] = s_W[i][n];
  }
}

extern "C" void kernel_launch(void* const* d_in, const int* in_sizes, int n_in,
                              void* d_out, int out_size, void* d_ws, size_t ws_size,
                              hipStream_t stream) {
  const float* img = (const float*)d_in[0];
  const float* W   = (const float*)d_in[1];
  float* out = (float*)d_out;
  float* ws  = (float*)d_ws;

  hipMemsetAsync(d_ws, 0, (size_t)WS_FLOATS * sizeof(float), stream);

  void* args[] = { (void*)&img, (void*)&W, (void*)&out, (void*)&ws };
  hipLaunchCooperativeKernel((const void*)snn_kernel, dim3(GRID), dim3(NTHR),
                             args, 0, stream);
}

// Round 2
// 5935.019 us; speedup vs baseline: 6.3961x; 6.3961x over previous
//
#include <hip/hip_runtime.h>

// SNN-MNIST forward + STDP, MI355X persistent cooperative kernel.
// Round 6: revert to the proven Round-4 skeleton (256 blocks x 256 thr,
// batch-row phase 1, LDS-staged dense STDP phase 2, 2 grid barriers/step).
// Change ONLY phase 2's compute mapping: 4 waves partition batch rows
// (r = 4k+w), each lane takes an (8i,4n) tile -> 6 ds_read_b128 per 64 FMA
// (was 3 per 16), halving LDS-pipe pressure. Wave partials combined in
// wave order via LDS transpose, then the same coherent Wt RMW as before.

#define T_STEPS 200
#define BATCH   256
#define INQ     784
#define NOUT    400
#define NP      512
#define GRID    256
#define NTHR    256

// ws layout (float offsets)
#define OFF_WT    0            // Wt [785][512] (row 784 = zero pad for gather)
#define OFF_SYN   401920       // syn [256][512]         (block-private)
#define OFF_MEM   532992       // mem [256][512]         (block-private)
#define OFF_SPPO  664064       // interleaved (spk,post): [256][1024]  (sc1)
#define OFF_TRA   926208       // trA [256][784]         (sc1)
#define OFF_TRB   1126912      // trB [256][784]         (sc1)
#define OFF_WIN   1327616      // int win[256]           (block-private)
#define OFF_FLAGS 1327872      // int flags[256]         (sc1)
#define OFF_BAR   1328128      // unsigned bar[4096]: hierarchical barrier
#define WS_FLOATS 1332224

// ---- agent-coherent (sc1) access helpers: L2 read-through / write-through ---
__device__ __forceinline__ float ld_coh(const float* p) {
  return __hip_atomic_load(p, __ATOMIC_RELAXED, __HIP_MEMORY_SCOPE_AGENT);
}
__device__ __forceinline__ float2 ld_coh2(const float* p) {
  union { unsigned long long u; float2 f; } c;
  c.u = __hip_atomic_load((const unsigned long long*)p, __ATOMIC_RELAXED,
                          __HIP_MEMORY_SCOPE_AGENT);
  return c.f;
}
__device__ __forceinline__ void st_coh(float* p, float v) {
  __hip_atomic_store(p, v, __ATOMIC_RELAXED, __HIP_MEMORY_SCOPE_AGENT);
}
__device__ __forceinline__ void st_coh2(float* p, float2 v) {
  union { unsigned long long u; float2 f; } c; c.f = v;
  __hip_atomic_store((unsigned long long*)p, c.u, __ATOMIC_RELAXED,
                     __HIP_MEMORY_SCOPE_AGENT);
}

__device__ __forceinline__ void gl_lds16(const float* g, float* l) {       // cached
  __builtin_amdgcn_global_load_lds(
      (const __attribute__((address_space(1))) void*)g,
      (__attribute__((address_space(3))) void*)l, 16, 0, 0);
}
__device__ __forceinline__ void gl_lds16c(const float* g, float* l) {      // sc1
  __builtin_amdgcn_global_load_lds(
      (const __attribute__((address_space(1))) void*)g,
      (__attribute__((address_space(3))) void*)l, 16, 0, 0x10);
}

// Hierarchical fence-free grid barrier, k = 1-based barrier ordinal.
// Level 1: 32 group counters (8 blocks each), 256 B apart. Level 2: 32-wide
// root. Monotonic counters (no reset/ABA). __syncthreads() before arrival
// drains vmcnt, making each block's write-through stores globally visible.
__device__ __forceinline__ void gbar(unsigned* bar, unsigned k, int blk) {
  __syncthreads();
  if (threadIdx.x == 0) {
    const int g = blk >> 3;
    unsigned* garr = bar + g * 64;
    unsigned* ggen = bar + g * 64 + 32;
    unsigned* rarr = bar + 32 * 64;
    unsigned* rgen = bar + 32 * 64 + 32;
    unsigned a = __hip_atomic_fetch_add(garr, 1u, __ATOMIC_RELAXED,
                                        __HIP_MEMORY_SCOPE_AGENT);
    if (a + 1u == k * 8u) {          // group leader = last arriver
      unsigned r = __hip_atomic_fetch_add(rarr, 1u, __ATOMIC_RELAXED,
                                          __HIP_MEMORY_SCOPE_AGENT);
      if (r + 1u == k * 32u) {       // root completer
        __hip_atomic_store(rgen, k, __ATOMIC_RELAXED, __HIP_MEMORY_SCOPE_AGENT);
      } else {
        while (__hip_atomic_load(rgen, __ATOMIC_RELAXED,
                                 __HIP_MEMORY_SCOPE_AGENT) < k)
          __builtin_amdgcn_s_sleep(1);
      }
      __hip_atomic_store(ggen, k, __ATOMIC_RELAXED, __HIP_MEMORY_SCOPE_AGENT);
    } else {
      while (__hip_atomic_load(ggen, __ATOMIC_RELAXED,
                               __HIP_MEMORY_SCOPE_AGENT) < k)
        __builtin_amdgcn_s_sleep(1);
    }
  }
  __syncthreads();
}

__device__ __forceinline__ float clip01(float x) {
  return fminf(fmaxf(x, 0.0f), 1.0f);
}

__global__ void __launch_bounds__(NTHR) snn_kernel(
    const float* __restrict__ img,   // [200][256][784]
    const float* __restrict__ Win,   // [400][784]
    float* __restrict__ out,         // mem_rec | spk_rec | W_final
    float* ws)
{
  float* Wt    = ws + OFF_WT;
  float* syn   = ws + OFF_SYN;
  float* mem   = ws + OFF_MEM;
  float* sppo  = ws + OFF_SPPO;
  float* trA   = ws + OFF_TRA;
  float* trB   = ws + OFF_TRB;
  int*   win   = (int*)(ws + OFF_WIN);
  unsigned* flags = (unsigned*)(ws + OFF_FLAGS);
  unsigned* bar   = (unsigned*)(ws + OFF_BAR);

  float* mem_rec = out;
  float* spk_rec = out + (size_t)T_STEPS * BATCH * NOUT;
  float* Wout    = out + (size_t)2 * T_STEPS * BATCH * NOUT;

  const int tid = threadIdx.x;
  const int blk = blockIdx.x;
  unsigned bt = 0;                    // barrier ordinal

  __shared__ int s_list[800];
  __shared__ int s_cnt;
  __shared__ int s_red[NTHR];
  __shared__ float stg[2][6144];      // [buf][tr | img | sppo], 32 b-rows x 64

  // ---- init: Wt[i][n] = Win[n][i], written coherently ----
  for (int e = blk * NTHR + tid; e < NOUT * INQ; e += GRID * NTHR) {
    int n = e / INQ, i = e % INQ;
    st_coh(Wt + (size_t)i * NP + n, Win[e]);
  }
  ++bt; gbar(bar, bt, blk);

  for (int t = 0; t < T_STEPS; ++t) {
    float* trC = (t & 1) ? trB : trA;   // pre_traces[t]
    float* trN = (t & 1) ? trA : trB;   // pre_traces[t+1]

    // ================= phase 1: block b = batch row =================
    {
      const int b = blk;
      const float* imrow = img + ((size_t)t * BATCH + b) * INQ;
      float* trCrow = trC + (size_t)b * INQ;
      float* trNrow = trN + (size_t)b * INQ;
      if (tid >= 64) {
        // waves 1-3: trace recurrence tr_{t+1} = 0.9*tr_t + img_t
        for (int i = tid - 64; i < INQ; i += NTHR - 64)
          st_coh(trNrow + i, fmaf(0.9f, ld_coh(trCrow + i), imrow[i]));
      } else {
        // wave 0: ordered active-index compaction, padded to multiple of 8
        int base = 0;
        for (int c = 0; c < INQ; c += 64) {
          int i = c + tid;
          bool act = (i < INQ) && (imrow[i] != 0.0f);
          unsigned long long m = __ballot(act);
          if (act) s_list[base + (int)__popcll(m & ((1ull << tid) - 1ull))] = i;
          base += (int)__popcll(m);
        }
        if (tid == 0) {
          int cr = (base + 7) & ~7;
          for (int j = base; j < cr; ++j) s_list[j] = 784;  // zero pad row
          s_cnt = cr;
        }
      }
      __syncthreads();
      const int cnt = s_cnt;            // multiple of 8
      const int anyPrev = (t > 0)
          ? (int)__hip_atomic_load(&flags[t - 1], __ATOMIC_RELAXED, __HIP_MEMORY_SCOPE_AGENT)
          : 0;
      const int wPrev = win[b];
      int localmin = 0x7fffffff;

      if (tid < 200) {
        const int n0 = tid * 2;
        const size_t sidx = (size_t)b * NP + n0;
        float2 sv = *(float2*)(syn + sidx);
        if (anyPrev) {
          if (n0     != wPrev) sv.x -= 0.1f;
          if (n0 + 1 != wPrev) sv.y -= 0.1f;
        }
        float c0 = 0.f, c1 = 0.f;
        for (int j = 0; j < cnt; j += 8) {   // 8 coherent loads in flight
          float2 w0 = ld_coh2(Wt + (size_t)s_list[j+0] * NP + n0);
          float2 w1 = ld_coh2(Wt + (size_t)s_list[j+1] * NP + n0);
          float2 w2 = ld_coh2(Wt + (size_t)s_list[j+2] * NP + n0);
          float2 w3 = ld_coh2(Wt + (size_t)s_list[j+3] * NP + n0);
          float2 w4 = ld_coh2(Wt + (size_t)s_list[j+4] * NP + n0);
          float2 w5 = ld_coh2(Wt + (size_t)s_list[j+5] * NP + n0);
          float2 w6 = ld_coh2(Wt + (size_t)s_list[j+6] * NP + n0);
          float2 w7 = ld_coh2(Wt + (size_t)s_list[j+7] * NP + n0);
          c0 += w0.x; c1 += w0.y;  c0 += w1.x; c1 += w1.y;
          c0 += w2.x; c1 += w2.y;  c0 += w3.x; c1 += w3.y;
          c0 += w4.x; c1 += w4.y;  c0 += w5.x; c1 += w5.y;
          c0 += w6.x; c1 += w6.y;  c0 += w7.x; c1 += w7.y;
        }
        float2 mv = *(float2*)(mem + sidx);
        float syn0 = fmaf(0.9f, sv.x, c0);
        float syn1 = fmaf(0.9f, sv.y, c1);
        float r0 = (mv.x > 1.0f) ? 1.0f : 0.0f;
        float r1 = (mv.y > 1.0f) ? 1.0f : 0.0f;
        float m0 = fmaf(0.8f, mv.x, syn0) - r0;
        float m1 = fmaf(0.8f, mv.y, syn1) - r1;
        float s0 = (m0 > 1.0f) ? 1.0f : 0.0f;
        float s1 = (m1 > 1.0f) ? 1.0f : 0.0f;
        *(float2*)(syn + sidx) = make_float2(syn0, syn1);
        *(float2*)(mem + sidx) = make_float2(m0, m1);
        // post trace; sppo is cross-XCD -> sc1 both ways
        float2 spA = ld_coh2(sppo + (size_t)b * 2 * NP + 2 * n0);
        float2 spB = ld_coh2(sppo + (size_t)b * 2 * NP + 2 * n0 + 2);
        float p0 = fmaf(0.9f, spA.y, s0);
        float p1 = fmaf(0.9f, spB.y, s1);
        st_coh2(sppo + (size_t)b * 2 * NP + 2 * n0,     make_float2(s0, p0));
        st_coh2(sppo + (size_t)b * 2 * NP + 2 * n0 + 2, make_float2(s1, p1));
        const size_t ridx = (size_t)t * BATCH * NOUT + (size_t)b * NOUT + n0;
        *(float2*)(mem_rec + ridx) = make_float2(m0, m1);
        *(float2*)(spk_rec + ridx) = make_float2(s0, s1);
        if      (s0 != 0.f) localmin = n0;
        else if (s1 != 0.f) localmin = n0 + 1;
      }
      s_red[tid] = localmin;
      __syncthreads();
      for (int o = NTHR / 2; o > 0; o >>= 1) {
        if (tid < o) s_red[tid] = min(s_red[tid], s_red[tid + o]);
        __syncthreads();
      }
      if (tid == 0) {
        int w = s_red[0];
        win[b] = (w == 0x7fffffff) ? 0 : w;
        if (w != 0x7fffffff)
          __hip_atomic_fetch_or(&flags[t], 1u, __ATOMIC_RELAXED, __HIP_MEMORY_SCOPE_AGENT);
      }
    }
    ++bt; gbar(bar, bt, blk);

    // ================= phase 2: STDP weight update (LDS-staged) =============
    // 169 blocks = 13 i-blocks (64 i) x 13 n-blocks (32 n).
    // Staging identical to Round-4. Compute: 4 waves partition the 32 staged
    // b-rows (r = 4k+w); each lane = (il,nl) 8x8 grid owns an (8i,4n) tile.
    if (blk < 169) {
      const int bi = blk / 13, bn = blk % 13;
      const int ib0 = bi * 64, nb0 = bn * 32;
      const int w = tid >> 6, l = tid & 63;
      const int brow0 = w * 4 + (l >> 4);
      int icol = ib0 + (l & 15) * 4;
      if (icol > INQ - 4) icol = INQ - 4;         // clamp (garbage, unused)
      const int scol = 2 * nb0 + (l & 15) * 4;
      const float* imgt = img + (size_t)t * BATCH * INQ;

      const int il = l >> 3, nl = l & 7;
      const int loff = il * 8;                    // tr/img lane col (8 floats)
      const int soff = nl * 8;                    // sppo lane col (4 (s,p) pairs)

      float a[8][4] = {};                         // (8i,4n) partial over b≡w mod 4

      // stage chunk c (32 b-rows): tr/sppo coherent (sc1), img cached
      #define STG(c, buf) {                                                     \
        int b0_ = (c) * 32;                                                     \
        for (int q = 0; q < 2; ++q) {                                           \
          int br = b0_ + q * 16 + brow0;                                        \
          float* dst = &stg[buf][(q * 16 + w * 4) * 64];                        \
          gl_lds16c(trC  + (size_t)br * INQ  + icol, dst);                      \
          gl_lds16 (imgt + (size_t)br * INQ  + icol, dst + 2048);               \
          gl_lds16c(sppo + (size_t)br * 1024 + scol, dst + 4096);               \
        }                                                                       \
      }

      STG(0, 0);
      for (int c = 0; c < 8; ++c) {
        const int buf = c & 1;
        if (c < 7) {
          STG(c + 1, buf ^ 1);
          __builtin_amdgcn_s_waitcnt(0x0F76);     // vmcnt(6): chunk c landed
        } else {
          __builtin_amdgcn_s_waitcnt(0x0F70);     // vmcnt(0)
        }
        __builtin_amdgcn_s_barrier();
        #pragma unroll 2
        for (int k = 0; k < 8; ++k) {
          const int r = 4 * k + w;                // this wave's b-rows
          const float4 tA = *(const float4*)&stg[buf][r * 64 + loff];
          const float4 tB = *(const float4*)&stg[buf][r * 64 + loff + 4];
          const float4 gA = *(const float4*)&stg[buf][2048 + r * 64 + loff];
          const float4 gB = *(const float4*)&stg[buf][2048 + r * 64 + loff + 4];
          const float4 sA = *(const float4*)&stg[buf][4096 + r * 64 + soff];
          const float4 sB = *(const float4*)&stg[buf][4096 + r * 64 + soff + 4];
          const float tv[8] = { tA.x, tA.y, tA.z, tA.w, tB.x, tB.y, tB.z, tB.w };
          const float gv[8] = { gA.x, gA.y, gA.z, gA.w, gB.x, gB.y, gB.z, gB.w };
          const float ap[4] = { 1e-3f * sA.x, 1e-3f * sA.z, 1e-3f * sB.x, 1e-3f * sB.z };
          const float am[4] = { 1e-3f * sA.y, 1e-3f * sA.w, 1e-3f * sB.y, 1e-3f * sB.w };
          #pragma unroll
          for (int ii = 0; ii < 8; ++ii)
            #pragma unroll
            for (int nn = 0; nn < 4; ++nn)
              a[ii][nn] = fmaf(tv[ii], ap[nn], fmaf(gv[ii], -am[nn], a[ii][nn]));
        }
        __builtin_amdgcn_s_waitcnt(0xC07F);       // lgkmcnt(0) only
        __builtin_amdgcn_s_barrier();
      }
      #undef STG

      // ---- combine wave partials in wave order, then coherent Wt RMW ----
      // part[w][k][l], k = ii*4+nn; [4][32][64] floats = 8192 <= 12288 avail.
      float* part = &stg[0][0];
      #pragma unroll
      for (int ii = 0; ii < 8; ++ii)
        #pragma unroll
        for (int nn = 0; nn < 4; ++nn)
          part[(w * 32 + (ii * 4 + nn)) * 64 + l] = a[ii][nn];
      __syncthreads();

      const int kb = (tid >> 6) * 8;              // this thread's 8 outputs
      float dsum[8];
      #pragma unroll
      for (int kk = 0; kk < 8; ++kk) {
        const int k = kb + kk;
        dsum[kk] = ((part[k * 64 + l] + part[2048 + k * 64 + l])
                    + part[4096 + k * 64 + l]) + part[6144 + k * 64 + l];
      }
      const int iBase = ib0 + (l >> 3) * 8;
      const int nBase = nb0 + (l & 7) * 4;
      if (nBase < NOUT) {
        #pragma unroll
        for (int j = 0; j < 2; ++j) {
          const int i = iBase + (kb >> 2) + j;
          if (i < INQ) {
            float* wp = Wt + (size_t)i * NP + nBase;
            float2 w2 = ld_coh2(wp);
            w2.x = clip01(w2.x + dsum[j * 4 + 0]);
            w2.y = clip01(w2.y + dsum[j * 4 + 1]);
            st_coh2(wp, w2);
            float2 w3 = ld_coh2(wp + 2);
            w3.x = clip01(w3.x + dsum[j * 4 + 2]);
            w3.y = clip01(w3.y + dsum[j * 4 + 3]);
            st_coh2(wp + 2, w3);
          }
        }
      }
    }
    ++bt; gbar(bar, bt, blk);
  }

  // ---- final: W_out[n][i] = Wt[i][n] ----
  for (int e = blk * NTHR + tid; e < NOUT * INQ; e += GRID * NTHR) {
    int n = e / INQ, i = e % INQ;
    Wout[e] = ld_coh(Wt + (size_t)i * NP + n);
  }
}

extern "C" void kernel_launch(void* const* d_in, const int* in_sizes, int n_in,
                              void* d_out, int out_size, void* d_ws, size_t ws_size,
                              hipStream_t stream) {
  const float* img = (const float*)d_in[0];
  const float* W   = (const float*)d_in[1];
  float* out = (float*)d_out;
  float* ws  = (float*)d_ws;

  hipMemsetAsync(d_ws, 0, (size_t)WS_FLOATS * sizeof(float), stream);

  void* args[] = { (void*)&img, (void*)&W, (void*)&out, (void*)&ws };
  hipLaunchCooperativeKernel((const void*)snn_kernel, dim3(GRID), dim3(NTHR),
                             args, 0, stream);
}

// Round 4
// 5862.012 us; speedup vs baseline: 6.4757x; 1.0125x over previous
//
#include <hip/hip_runtime.h>

// SNN-MNIST forward + STDP, MI355X persistent cooperative kernel.
// Round 8: bisect of the failed Round 7. Phase 2 (STDP) is Round-6
// VERBATIM (verified). Kept from Round 7: (a) trace recurrence +
// list build moved from phase 1 into the phase-2 epoch (double-buffered
// block-local s_list, parallel 4-wave ballot build); (b) phase-1 gather
// 16-in-flight with 16-padded lists; (c) shuffle win-reduce; (d) hoisted
// sppo loads. If this passes, Round-7's failure is isolated to the
// phase-2 retile.

#define T_STEPS 200
#define BATCH   256
#define INQ     784
#define NOUT    400
#define NP      512
#define GRID    256
#define NTHR    256
#define IMSZ    200704           // 256*784

// ws layout (float offsets) — unchanged from Round 6
#define OFF_WT    0            // Wt [785][512] (row 784 = zero pad for gather)
#define OFF_SYN   401920       // syn [256][512]         (block-private)
#define OFF_MEM   532992       // mem [256][512]         (block-private)
#define OFF_SPPO  664064       // interleaved (spk,post): [256][1024]  (sc1)
#define OFF_TRA   926208       // trA [256][784]         (sc1)
#define OFF_TRB   1126912      // trB [256][784]         (sc1)
#define OFF_WIN   1327616      // int win[256]           (block-private)
#define OFF_FLAGS 1327872      // int flags[256]         (sc1)
#define OFF_BAR   1328128      // unsigned bar[4096]: hierarchical barrier
#define WS_FLOATS 1332224

typedef unsigned long long ull;

// ---- agent-coherent (sc1) access helpers ----
__device__ __forceinline__ float ld_coh(const float* p) {
  return __hip_atomic_load(p, __ATOMIC_RELAXED, __HIP_MEMORY_SCOPE_AGENT);
}
__device__ __forceinline__ float2 ld_coh2(const float* p) {
  union { ull u; float2 f; } c;
  c.u = __hip_atomic_load((const ull*)p, __ATOMIC_RELAXED, __HIP_MEMORY_SCOPE_AGENT);
  return c.f;
}
__device__ __forceinline__ void st_coh(float* p, float v) {
  __hip_atomic_store(p, v, __ATOMIC_RELAXED, __HIP_MEMORY_SCOPE_AGENT);
}
__device__ __forceinline__ void st_coh2(float* p, float2 v) {
  union { ull u; float2 f; } c; c.f = v;
  __hip_atomic_store((ull*)p, c.u, __ATOMIC_RELAXED, __HIP_MEMORY_SCOPE_AGENT);
}

__device__ __forceinline__ void gl_lds16(const float* g, float* l) {       // cached
  __builtin_amdgcn_global_load_lds(
      (const __attribute__((address_space(1))) void*)g,
      (__attribute__((address_space(3))) void*)l, 16, 0, 0);
}
__device__ __forceinline__ void gl_lds16c(const float* g, float* l) {      // sc1
  __builtin_amdgcn_global_load_lds(
      (const __attribute__((address_space(1))) void*)g,
      (__attribute__((address_space(3))) void*)l, 16, 0, 0x10);
}

// Hierarchical fence-free grid barrier (32 groups x 8), monotonic counters.
__device__ __forceinline__ void gbar(unsigned* bar, unsigned k, int blk) {
  __syncthreads();
  if (threadIdx.x == 0) {
    const int g = blk >> 3;
    unsigned* garr = bar + g * 64;
    unsigned* ggen = bar + g * 64 + 32;
    unsigned* rarr = bar + 32 * 64;
    unsigned* rgen = bar + 32 * 64 + 32;
    unsigned a = __hip_atomic_fetch_add(garr, 1u, __ATOMIC_RELAXED,
                                        __HIP_MEMORY_SCOPE_AGENT);
    if (a + 1u == k * 8u) {
      unsigned r = __hip_atomic_fetch_add(rarr, 1u, __ATOMIC_RELAXED,
                                          __HIP_MEMORY_SCOPE_AGENT);
      if (r + 1u == k * 32u) {
        __hip_atomic_store(rgen, k, __ATOMIC_RELAXED, __HIP_MEMORY_SCOPE_AGENT);
      } else {
        while (__hip_atomic_load(rgen, __ATOMIC_RELAXED,
                                 __HIP_MEMORY_SCOPE_AGENT) < k)
          __builtin_amdgcn_s_sleep(1);
      }
      __hip_atomic_store(ggen, k, __ATOMIC_RELAXED, __HIP_MEMORY_SCOPE_AGENT);
    } else {
      while (__hip_atomic_load(ggen, __ATOMIC_RELAXED,
                               __HIP_MEMORY_SCOPE_AGENT) < k)
        __builtin_amdgcn_s_sleep(1);
    }
  }
  __syncthreads();
}

__device__ __forceinline__ float clip01(float x) {
  return fminf(fmaxf(x, 0.0f), 1.0f);
}

__global__ void __launch_bounds__(NTHR) snn_kernel(
    const float* __restrict__ img,   // [200][256][784]
    const float* __restrict__ Win,   // [400][784]
    float* __restrict__ out,         // mem_rec | spk_rec | W_final
    float* ws)
{
  float* Wt    = ws + OFF_WT;
  float* syn   = ws + OFF_SYN;
  float* mem   = ws + OFF_MEM;
  float* sppo  = ws + OFF_SPPO;
  float* trA   = ws + OFF_TRA;
  float* trB   = ws + OFF_TRB;
  int*   win   = (int*)(ws + OFF_WIN);
  unsigned* flags = (unsigned*)(ws + OFF_FLAGS);
  unsigned* bar   = (unsigned*)(ws + OFF_BAR);

  float* mem_rec = out;
  float* spk_rec = out + (size_t)T_STEPS * BATCH * NOUT;
  float* Wout    = out + (size_t)2 * T_STEPS * BATCH * NOUT;

  const int tid = threadIdx.x;
  const int blk = blockIdx.x;
  const int wv = tid >> 6, ln = tid & 63;
  unsigned bt = 0;

  __shared__ int   s_list[2][800];
  __shared__ int   s_cnt2[2];
  __shared__ ull   s_msk[13];
  __shared__ int   s_pref[14];
  __shared__ int   s_red4[4];
  __shared__ float stg[2][6144];      // [buf][tr | img | sppo], 32 b-rows x 64

  // Parallel ordered active-index compaction for img[tt] row blk -> s_list[slot].
  auto build_list = [&](int tt, int slot) {
    const float* row = img + (size_t)tt * IMSZ + (size_t)blk * INQ;
    for (int c = wv; c < 13; c += 4) {
      int i = c * 64 + ln;
      bool act = (i < INQ) && (row[i] != 0.0f);
      ull m = __ballot(act);
      if (ln == 0) s_msk[c] = m;
    }
    __syncthreads();
    if (tid == 0) {
      int acc = 0;
      for (int c = 0; c < 13; ++c) { s_pref[c] = acc; acc += (int)__popcll(s_msk[c]); }
      s_pref[13] = acc;
      s_cnt2[slot] = (acc + 15) & ~15;
    }
    __syncthreads();
    for (int c = wv; c < 13; c += 4) {
      ull m = s_msk[c];
      if ((m >> ln) & 1ull)
        s_list[slot][s_pref[c] + (int)__popcll(m & ((1ull << ln) - 1ull))] =
            c * 64 + ln;
    }
    int base = s_pref[13];
    int cr = (base + 15) & ~15;
    if (tid < cr - base) s_list[slot][base + tid] = 784;   // zero-row sentinel
  };

  // ---- prologue: Wt[i][n] = Win[n][i]; list(0) ----
  for (int e = blk * NTHR + tid; e < NOUT * INQ; e += GRID * NTHR) {
    int n = e / INQ, i = e % INQ;
    st_coh(Wt + (size_t)i * NP + n, Win[e]);
  }
  build_list(0, 0);
  ++bt; gbar(bar, bt, blk);

  for (int t = 0; t < T_STEPS; ++t) {
    float* trC = (t & 1) ? trB : trA;   // pre_traces[t]
    float* trN = (t & 1) ? trA : trB;   // pre_traces[t+1]

    // ================= phase 1: block b = batch row (gather + state) ========
    {
      const int b = blk;
      const int slot = t & 1;
      const int cnt = s_cnt2[slot];
      const int anyPrev = (t > 0)
          ? (int)__hip_atomic_load(&flags[t - 1], __ATOMIC_RELAXED, __HIP_MEMORY_SCOPE_AGENT)
          : 0;
      const int wPrev = win[b];
      int localmin = 0x7fffffff;

      if (tid < 200) {
        const int n0 = tid * 2;
        const size_t sidx = (size_t)b * NP + n0;
        // hoisted sppo loads (latency hidden under gather)
        float2 spA = ld_coh2(sppo + (size_t)b * 1024 + 2 * n0);
        float2 spB = ld_coh2(sppo + (size_t)b * 1024 + 2 * n0 + 2);
        float2 sv = *(float2*)(syn + sidx);
        if (anyPrev) {
          if (n0     != wPrev) sv.x -= 0.1f;
          if (n0 + 1 != wPrev) sv.y -= 0.1f;
        }
        float c0 = 0.f, c1 = 0.f;
        for (int j = 0; j < cnt; j += 16) {   // 16 coherent loads in flight
          float2 q0  = ld_coh2(Wt + (size_t)s_list[slot][j+0]  * NP + n0);
          float2 q1  = ld_coh2(Wt + (size_t)s_list[slot][j+1]  * NP + n0);
          float2 q2  = ld_coh2(Wt + (size_t)s_list[slot][j+2]  * NP + n0);
          float2 q3  = ld_coh2(Wt + (size_t)s_list[slot][j+3]  * NP + n0);
          float2 q4  = ld_coh2(Wt + (size_t)s_list[slot][j+4]  * NP + n0);
          float2 q5  = ld_coh2(Wt + (size_t)s_list[slot][j+5]  * NP + n0);
          float2 q6  = ld_coh2(Wt + (size_t)s_list[slot][j+6]  * NP + n0);
          float2 q7  = ld_coh2(Wt + (size_t)s_list[slot][j+7]  * NP + n0);
          float2 q8  = ld_coh2(Wt + (size_t)s_list[slot][j+8]  * NP + n0);
          float2 q9  = ld_coh2(Wt + (size_t)s_list[slot][j+9]  * NP + n0);
          float2 q10 = ld_coh2(Wt + (size_t)s_list[slot][j+10] * NP + n0);
          float2 q11 = ld_coh2(Wt + (size_t)s_list[slot][j+11] * NP + n0);
          float2 q12 = ld_coh2(Wt + (size_t)s_list[slot][j+12] * NP + n0);
          float2 q13 = ld_coh2(Wt + (size_t)s_list[slot][j+13] * NP + n0);
          float2 q14 = ld_coh2(Wt + (size_t)s_list[slot][j+14] * NP + n0);
          float2 q15 = ld_coh2(Wt + (size_t)s_list[slot][j+15] * NP + n0);
          c0 += q0.x;  c1 += q0.y;   c0 += q1.x;  c1 += q1.y;
          c0 += q2.x;  c1 += q2.y;   c0 += q3.x;  c1 += q3.y;
          c0 += q4.x;  c1 += q4.y;   c0 += q5.x;  c1 += q5.y;
          c0 += q6.x;  c1 += q6.y;   c0 += q7.x;  c1 += q7.y;
          c0 += q8.x;  c1 += q8.y;   c0 += q9.x;  c1 += q9.y;
          c0 += q10.x; c1 += q10.y;  c0 += q11.x; c1 += q11.y;
          c0 += q12.x; c1 += q12.y;  c0 += q13.x; c1 += q13.y;
          c0 += q14.x; c1 += q14.y;  c0 += q15.x; c1 += q15.y;
        }
        float2 mv = *(float2*)(mem + sidx);
        float syn0 = fmaf(0.9f, sv.x, c0);
        float syn1 = fmaf(0.9f, sv.y, c1);
        float r0 = (mv.x > 1.0f) ? 1.0f : 0.0f;
        float r1 = (mv.y > 1.0f) ? 1.0f : 0.0f;
        float m0 = fmaf(0.8f, mv.x, syn0) - r0;
        float m1 = fmaf(0.8f, mv.y, syn1) - r1;
        float s0 = (m0 > 1.0f) ? 1.0f : 0.0f;
        float s1 = (m1 > 1.0f) ? 1.0f : 0.0f;
        *(float2*)(syn + sidx) = make_float2(syn0, syn1);
        *(float2*)(mem + sidx) = make_float2(m0, m1);
        float p0 = fmaf(0.9f, spA.y, s0);
        float p1 = fmaf(0.9f, spB.y, s1);
        st_coh2(sppo + (size_t)b * 1024 + 2 * n0,     make_float2(s0, p0));
        st_coh2(sppo + (size_t)b * 1024 + 2 * n0 + 2, make_float2(s1, p1));
        const size_t ridx = (size_t)t * BATCH * NOUT + (size_t)b * NOUT + n0;
        *(float2*)(mem_rec + ridx) = make_float2(m0, m1);
        *(float2*)(spk_rec + ridx) = make_float2(s0, s1);
        if      (s0 != 0.f) localmin = n0;
        else if (s1 != 0.f) localmin = n0 + 1;
      }
      int v = localmin;
      #pragma unroll
      for (int s = 1; s < 64; s <<= 1) v = min(v, __shfl_xor(v, s));
      if (ln == 0) s_red4[wv] = v;
      __syncthreads();
      if (tid == 0) {
        int w = min(min(s_red4[0], s_red4[1]), min(s_red4[2], s_red4[3]));
        win[b] = (w == 0x7fffffff) ? 0 : w;
        if (w != 0x7fffffff)
          __hip_atomic_fetch_or(&flags[t], 1u, __ATOMIC_RELAXED, __HIP_MEMORY_SCOPE_AGENT);
      }
    }
    ++bt; gbar(bar, bt, blk);

    // ================= phase 2: STDP weight update — ROUND-6 VERBATIM =======
    // 169 blocks = 13 i-blocks (64 i) x 13 n-blocks (32 n).
    // 4 waves partition the 32 staged b-rows (r = 4k+w); each lane = (il,nl)
    // 8x8 grid owns an (8i,4n) tile.
    if (blk < 169) {
      const int bi = blk / 13, bn = blk % 13;
      const int ib0 = bi * 64, nb0 = bn * 32;
      const int w = tid >> 6, l = tid & 63;
      const int brow0 = w * 4 + (l >> 4);
      int icol = ib0 + (l & 15) * 4;
      if (icol > INQ - 4) icol = INQ - 4;         // clamp (garbage, unused)
      const int scol = 2 * nb0 + (l & 15) * 4;
      const float* imgt = img + (size_t)t * BATCH * INQ;

      const int il = l >> 3, nl = l & 7;
      const int loff = il * 8;                    // tr/img lane col (8 floats)
      const int soff = nl * 8;                    // sppo lane col (4 (s,p) pairs)

      float a[8][4] = {};                         // (8i,4n) partial over b≡w mod 4

      // stage chunk c (32 b-rows): tr/sppo coherent (sc1), img cached
      #define STG(c, buf) {                                                     \
        int b0_ = (c) * 32;                                                     \
        for (int q = 0; q < 2; ++q) {                                           \
          int br = b0_ + q * 16 + brow0;                                        \
          float* dst = &stg[buf][(q * 16 + w * 4) * 64];                        \
          gl_lds16c(trC  + (size_t)br * INQ  + icol, dst);                      \
          gl_lds16 (imgt + (size_t)br * INQ  + icol, dst + 2048);               \
          gl_lds16c(sppo + (size_t)br * 1024 + scol, dst + 4096);               \
        }                                                                       \
      }

      STG(0, 0);
      for (int c = 0; c < 8; ++c) {
        const int buf = c & 1;
        if (c < 7) {
          STG(c + 1, buf ^ 1);
          __builtin_amdgcn_s_waitcnt(0x0F76);     // vmcnt(6): chunk c landed
        } else {
          __builtin_amdgcn_s_waitcnt(0x0F70);     // vmcnt(0)
        }
        __builtin_amdgcn_s_barrier();
        #pragma unroll 2
        for (int k = 0; k < 8; ++k) {
          const int r = 4 * k + w;                // this wave's b-rows
          const float4 tA = *(const float4*)&stg[buf][r * 64 + loff];
          const float4 tB = *(const float4*)&stg[buf][r * 64 + loff + 4];
          const float4 gA = *(const float4*)&stg[buf][2048 + r * 64 + loff];
          const float4 gB = *(const float4*)&stg[buf][2048 + r * 64 + loff + 4];
          const float4 sA = *(const float4*)&stg[buf][4096 + r * 64 + soff];
          const float4 sB = *(const float4*)&stg[buf][4096 + r * 64 + soff + 4];
          const float tv[8] = { tA.x, tA.y, tA.z, tA.w, tB.x, tB.y, tB.z, tB.w };
          const float gv[8] = { gA.x, gA.y, gA.z, gA.w, gB.x, gB.y, gB.z, gB.w };
          const float ap[4] = { 1e-3f * sA.x, 1e-3f * sA.z, 1e-3f * sB.x, 1e-3f * sB.z };
          const float am[4] = { 1e-3f * sA.y, 1e-3f * sA.w, 1e-3f * sB.y, 1e-3f * sB.w };
          #pragma unroll
          for (int ii = 0; ii < 8; ++ii)
            #pragma unroll
            for (int nn = 0; nn < 4; ++nn)
              a[ii][nn] = fmaf(tv[ii], ap[nn], fmaf(gv[ii], -am[nn], a[ii][nn]));
        }
        __builtin_amdgcn_s_waitcnt(0xC07F);       // lgkmcnt(0) only
        __builtin_amdgcn_s_barrier();
      }
      #undef STG

      // ---- combine wave partials in wave order, then coherent Wt RMW ----
      // part[w][k][l], k = ii*4+nn; [4][32][64] floats = 8192 <= 12288 avail.
      float* part = &stg[0][0];
      #pragma unroll
      for (int ii = 0; ii < 8; ++ii)
        #pragma unroll
        for (int nn = 0; nn < 4; ++nn)
          part[(w * 32 + (ii * 4 + nn)) * 64 + l] = a[ii][nn];
      __syncthreads();

      const int kb = (tid >> 6) * 8;              // this thread's 8 outputs
      float dsum[8];
      #pragma unroll
      for (int kk = 0; kk < 8; ++kk) {
        const int k = kb + kk;
        dsum[kk] = ((part[k * 64 + l] + part[2048 + k * 64 + l])
                    + part[4096 + k * 64 + l]) + part[6144 + k * 64 + l];
      }
      const int iBase = ib0 + (l >> 3) * 8;
      const int nBase = nb0 + (l & 7) * 4;
      if (nBase < NOUT) {
        #pragma unroll
        for (int j = 0; j < 2; ++j) {
          const int i = iBase + (kb >> 2) + j;
          if (i < INQ) {
            float* wp = Wt + (size_t)i * NP + nBase;
            float2 w2 = ld_coh2(wp);
            w2.x = clip01(w2.x + dsum[j * 4 + 0]);
            w2.y = clip01(w2.y + dsum[j * 4 + 1]);
            st_coh2(wp, w2);
            float2 w3 = ld_coh2(wp + 2);
            w3.x = clip01(w3.x + dsum[j * 4 + 2]);
            w3.y = clip01(w3.y + dsum[j * 4 + 3]);
            st_coh2(wp + 2, w3);
          }
        }
      }
    }

    // ---- all blocks: trace recurrence + next list (own row), in P2 epoch ---
    {
      const float* imrow = img + (size_t)t * IMSZ + (size_t)blk * INQ;
      const float* trCrow = trC + (size_t)blk * INQ;
      float* trNrow = trN + (size_t)blk * INQ;
      for (int i = tid * 2; i < INQ; i += 2 * NTHR) {
        float2 o = ld_coh2(trCrow + i);
        float2 iv = *(const float2*)(imrow + i);
        st_coh2(trNrow + i, make_float2(fmaf(0.9f, o.x, iv.x),
                                        fmaf(0.9f, o.y, iv.y)));
      }
    }
    if (t + 1 < T_STEPS) build_list(t + 1, (t + 1) & 1);

    ++bt; gbar(bar, bt, blk);
  }

  // ---- final: W_out[n][i] = Wt[i][n] ----
  for (int e = blk * NTHR + tid; e < NOUT * INQ; e += GRID * NTHR) {
    int n = e / INQ, i = e % INQ;
    Wout[e] = ld_coh(Wt + (size_t)i * NP + n);
  }
}

extern "C" void kernel_launch(void* const* d_in, const int* in_sizes, int n_in,
                              void* d_out, int out_size, void* d_ws, size_t ws_size,
                              hipStream_t stream) {
  const float* img = (const float*)d_in[0];
  const float* W   = (const float*)d_in[1];
  float* out = (float*)d_out;
  float* ws  = (float*)d_ws;

  hipMemsetAsync(d_ws, 0, (size_t)WS_FLOATS * sizeof(float), stream);

  void* args[] = { (void*)&img, (void*)&W, (void*)&out, (void*)&ws };
  hipLaunchCooperativeKernel((const void*)snn_kernel, dim3(GRID), dim3(NTHR),
                             args, 0, stream);
}

// Round 5
// 5000.180 us; speedup vs baseline: 7.5919x; 1.1724x over previous
//
#include <hip/hip_runtime.h>

// SNN-MNIST forward + STDP, MI355X persistent cooperative kernel.
// Round 9: occupancy 2x (NTHR 256 -> 512, 8 waves/CU, 2/SIMD) with the
// R6/R8-verified algorithm unchanged. Phase 1: 400 threads x 1 neuron
// (scalar sc1 gather, same ascending-i order). Phase 2: 8 waves stage
// 4 rows each (vmcnt(3)), compute rows r == w (mod 8) with the verbatim
// R6 inner body (4 k-iters); two-round 4-wave LDS combine in fixed order;
// Wt RMW = 1 i x 4 n per thread. Latency (sc1, staging, barriers) now
// overlaps across 2 waves/SIMD instead of hitting idle SIMDs.

#define T_STEPS 200
#define BATCH   256
#define INQ     784
#define NOUT    400
#define NP      512
#define GRID    256
#define NTHR    512
#define IMSZ    200704           // 256*784

// ws layout (float offsets) — unchanged
#define OFF_WT    0            // Wt [785][512] (row 784 = zero pad for gather)
#define OFF_SYN   401920       // syn [256][512]         (block-private)
#define OFF_MEM   532992       // mem [256][512]         (block-private)
#define OFF_SPPO  664064       // interleaved (spk,post): [256][1024]  (sc1)
#define OFF_TRA   926208       // trA [256][784]         (sc1)
#define OFF_TRB   1126912      // trB [256][784]         (sc1)
#define OFF_WIN   1327616      // int win[256]           (block-private)
#define OFF_FLAGS 1327872      // int flags[256]         (sc1)
#define OFF_BAR   1328128      // unsigned bar[4096]: hierarchical barrier
#define WS_FLOATS 1332224

typedef unsigned long long ull;

// ---- agent-coherent (sc1) access helpers ----
__device__ __forceinline__ float ld_coh(const float* p) {
  return __hip_atomic_load(p, __ATOMIC_RELAXED, __HIP_MEMORY_SCOPE_AGENT);
}
__device__ __forceinline__ float2 ld_coh2(const float* p) {
  union { ull u; float2 f; } c;
  c.u = __hip_atomic_load((const ull*)p, __ATOMIC_RELAXED, __HIP_MEMORY_SCOPE_AGENT);
  return c.f;
}
__device__ __forceinline__ void st_coh(float* p, float v) {
  __hip_atomic_store(p, v, __ATOMIC_RELAXED, __HIP_MEMORY_SCOPE_AGENT);
}
__device__ __forceinline__ void st_coh2(float* p, float2 v) {
  union { ull u; float2 f; } c; c.f = v;
  __hip_atomic_store((ull*)p, c.u, __ATOMIC_RELAXED, __HIP_MEMORY_SCOPE_AGENT);
}

__device__ __forceinline__ void gl_lds16(const float* g, float* l) {       // cached
  __builtin_amdgcn_global_load_lds(
      (const __attribute__((address_space(1))) void*)g,
      (__attribute__((address_space(3))) void*)l, 16, 0, 0);
}
__device__ __forceinline__ void gl_lds16c(const float* g, float* l) {      // sc1
  __builtin_amdgcn_global_load_lds(
      (const __attribute__((address_space(1))) void*)g,
      (__attribute__((address_space(3))) void*)l, 16, 0, 0x10);
}

// Hierarchical fence-free grid barrier (32 groups x 8), monotonic counters.
__device__ __forceinline__ void gbar(unsigned* bar, unsigned k, int blk) {
  __syncthreads();
  if (threadIdx.x == 0) {
    const int g = blk >> 3;
    unsigned* garr = bar + g * 64;
    unsigned* ggen = bar + g * 64 + 32;
    unsigned* rarr = bar + 32 * 64;
    unsigned* rgen = bar + 32 * 64 + 32;
    unsigned a = __hip_atomic_fetch_add(garr, 1u, __ATOMIC_RELAXED,
                                        __HIP_MEMORY_SCOPE_AGENT);
    if (a + 1u == k * 8u) {
      unsigned r = __hip_atomic_fetch_add(rarr, 1u, __ATOMIC_RELAXED,
                                          __HIP_MEMORY_SCOPE_AGENT);
      if (r + 1u == k * 32u) {
        __hip_atomic_store(rgen, k, __ATOMIC_RELAXED, __HIP_MEMORY_SCOPE_AGENT);
      } else {
        while (__hip_atomic_load(rgen, __ATOMIC_RELAXED,
                                 __HIP_MEMORY_SCOPE_AGENT) < k)
          __builtin_amdgcn_s_sleep(1);
      }
      __hip_atomic_store(ggen, k, __ATOMIC_RELAXED, __HIP_MEMORY_SCOPE_AGENT);
    } else {
      while (__hip_atomic_load(ggen, __ATOMIC_RELAXED,
                               __HIP_MEMORY_SCOPE_AGENT) < k)
        __builtin_amdgcn_s_sleep(1);
    }
  }
  __syncthreads();
}

__device__ __forceinline__ float clip01(float x) {
  return fminf(fmaxf(x, 0.0f), 1.0f);
}

__global__ void __launch_bounds__(NTHR) snn_kernel(
    const float* __restrict__ img,   // [200][256][784]
    const float* __restrict__ Win,   // [400][784]
    float* __restrict__ out,         // mem_rec | spk_rec | W_final
    float* ws)
{
  float* Wt    = ws + OFF_WT;
  float* syn   = ws + OFF_SYN;
  float* mem   = ws + OFF_MEM;
  float* sppo  = ws + OFF_SPPO;
  float* trA   = ws + OFF_TRA;
  float* trB   = ws + OFF_TRB;
  int*   win   = (int*)(ws + OFF_WIN);
  unsigned* flags = (unsigned*)(ws + OFF_FLAGS);
  unsigned* bar   = (unsigned*)(ws + OFF_BAR);

  float* mem_rec = out;
  float* spk_rec = out + (size_t)T_STEPS * BATCH * NOUT;
  float* Wout    = out + (size_t)2 * T_STEPS * BATCH * NOUT;

  const int tid = threadIdx.x;
  const int blk = blockIdx.x;
  const int wv = tid >> 6, ln = tid & 63;
  unsigned bt = 0;

  __shared__ int   s_list[2][800];
  __shared__ int   s_cnt2[2];
  __shared__ ull   s_msk[13];
  __shared__ int   s_pref[14];
  __shared__ int   s_red8[8];
  __shared__ float stg[2][6144];      // [buf][tr | img | sppo], 32 b-rows x 64

  // Parallel ordered active-index compaction for img[tt] row blk -> s_list[slot].
  auto build_list = [&](int tt, int slot) {
    const float* row = img + (size_t)tt * IMSZ + (size_t)blk * INQ;
    for (int c = wv; c < 13; c += 8) {
      int i = c * 64 + ln;
      bool act = (i < INQ) && (row[i] != 0.0f);
      ull m = __ballot(act);
      if (ln == 0) s_msk[c] = m;
    }
    __syncthreads();
    if (tid == 0) {
      int acc = 0;
      for (int c = 0; c < 13; ++c) { s_pref[c] = acc; acc += (int)__popcll(s_msk[c]); }
      s_pref[13] = acc;
      s_cnt2[slot] = (acc + 15) & ~15;
    }
    __syncthreads();
    for (int c = wv; c < 13; c += 8) {
      ull m = s_msk[c];
      if ((m >> ln) & 1ull)
        s_list[slot][s_pref[c] + (int)__popcll(m & ((1ull << ln) - 1ull))] =
            c * 64 + ln;
    }
    int base = s_pref[13];
    int cr = (base + 15) & ~15;
    if (tid < cr - base) s_list[slot][base + tid] = 784;   // zero-row sentinel
  };

  // ---- prologue: Wt[i][n] = Win[n][i]; list(0) ----
  for (int e = blk * NTHR + tid; e < NOUT * INQ; e += GRID * NTHR) {
    int n = e / INQ, i = e % INQ;
    st_coh(Wt + (size_t)i * NP + n, Win[e]);
  }
  build_list(0, 0);
  ++bt; gbar(bar, bt, blk);

  for (int t = 0; t < T_STEPS; ++t) {
    float* trC = (t & 1) ? trB : trA;   // pre_traces[t]
    float* trN = (t & 1) ? trA : trB;   // pre_traces[t+1]

    // ================= phase 1: block b = batch row (gather + state) ========
    {
      const int b = blk;
      const int slot = t & 1;
      const int cnt = s_cnt2[slot];
      const int anyPrev = (t > 0)
          ? (int)__hip_atomic_load(&flags[t - 1], __ATOMIC_RELAXED, __HIP_MEMORY_SCOPE_AGENT)
          : 0;
      const int wPrev = win[b];
      int localmin = 0x7fffffff;

      if (tid < NOUT) {
        const int n = tid;                 // 1 neuron per thread
        const size_t sidx = (size_t)b * NP + n;
        // hoisted sppo load (latency hidden under gather)
        float2 sp = ld_coh2(sppo + (size_t)b * 1024 + 2 * n);
        float sv = syn[sidx];
        if (anyPrev && n != wPrev) sv -= 0.1f;
        float c0 = 0.f;
        const int* lrow = s_list[slot];
        for (int j = 0; j < cnt; j += 16) {   // 16 coherent scalar loads in flight
          float q0  = ld_coh(Wt + (size_t)lrow[j+0]  * NP + n);
          float q1  = ld_coh(Wt + (size_t)lrow[j+1]  * NP + n);
          float q2  = ld_coh(Wt + (size_t)lrow[j+2]  * NP + n);
          float q3  = ld_coh(Wt + (size_t)lrow[j+3]  * NP + n);
          float q4  = ld_coh(Wt + (size_t)lrow[j+4]  * NP + n);
          float q5  = ld_coh(Wt + (size_t)lrow[j+5]  * NP + n);
          float q6  = ld_coh(Wt + (size_t)lrow[j+6]  * NP + n);
          float q7  = ld_coh(Wt + (size_t)lrow[j+7]  * NP + n);
          float q8  = ld_coh(Wt + (size_t)lrow[j+8]  * NP + n);
          float q9  = ld_coh(Wt + (size_t)lrow[j+9]  * NP + n);
          float q10 = ld_coh(Wt + (size_t)lrow[j+10] * NP + n);
          float q11 = ld_coh(Wt + (size_t)lrow[j+11] * NP + n);
          float q12 = ld_coh(Wt + (size_t)lrow[j+12] * NP + n);
          float q13 = ld_coh(Wt + (size_t)lrow[j+13] * NP + n);
          float q14 = ld_coh(Wt + (size_t)lrow[j+14] * NP + n);
          float q15 = ld_coh(Wt + (size_t)lrow[j+15] * NP + n);
          c0 += q0;  c0 += q1;  c0 += q2;  c0 += q3;
          c0 += q4;  c0 += q5;  c0 += q6;  c0 += q7;
          c0 += q8;  c0 += q9;  c0 += q10; c0 += q11;
          c0 += q12; c0 += q13; c0 += q14; c0 += q15;
        }
        float mv = mem[sidx];
        float syn0 = fmaf(0.9f, sv, c0);
        float r0 = (mv > 1.0f) ? 1.0f : 0.0f;
        float m0 = fmaf(0.8f, mv, syn0) - r0;
        float s0 = (m0 > 1.0f) ? 1.0f : 0.0f;
        syn[sidx] = syn0;
        mem[sidx] = m0;
        float p0 = fmaf(0.9f, sp.y, s0);
        st_coh2(sppo + (size_t)b * 1024 + 2 * n, make_float2(s0, p0));
        const size_t ridx = (size_t)t * BATCH * NOUT + (size_t)b * NOUT + n;
        mem_rec[ridx] = m0;
        spk_rec[ridx] = s0;
        if (s0 != 0.f) localmin = n;
      }
      int v = localmin;
      #pragma unroll
      for (int s = 1; s < 64; s <<= 1) v = min(v, __shfl_xor(v, s));
      if (ln == 0) s_red8[wv] = v;
      __syncthreads();
      if (tid == 0) {
        int w = s_red8[0];
        #pragma unroll
        for (int q = 1; q < 8; ++q) w = min(w, s_red8[q]);
        win[b] = (w == 0x7fffffff) ? 0 : w;
        if (w != 0x7fffffff)
          __hip_atomic_fetch_or(&flags[t], 1u, __ATOMIC_RELAXED, __HIP_MEMORY_SCOPE_AGENT);
      }
    }
    ++bt; gbar(bar, bt, blk);

    // ================= phase 2: STDP weight update (LDS-staged) =============
    // 169 blocks = 13 i-blocks (64 i) x 13 n-blocks (32 n). 8 waves: wave w
    // stages rows w*4..w*4+3 per chunk (3 gl_lds16/thread, vmcnt(3)) and
    // computes rows r == w (mod 8), 4 k-iters of the verbatim R6 body.
    if (blk < 169) {
      const int bi = blk / 13, bn = blk % 13;
      const int ib0 = bi * 64, nb0 = bn * 32;
      const int w = wv, l = ln;
      const int brow0 = w * 4 + (l >> 4);
      int icol = ib0 + (l & 15) * 4;
      if (icol > INQ - 4) icol = INQ - 4;         // clamp (garbage, unused)
      const int scol = 2 * nb0 + (l & 15) * 4;
      const float* imgt = img + (size_t)t * BATCH * INQ;

      const int il = l >> 3, nl = l & 7;
      const int loff = il * 8;                    // tr/img lane col (8 floats)
      const int soff = nl * 8;                    // sppo lane col (4 (s,p) pairs)

      float a[8][4] = {};                         // (8i,4n) partial over b≡w mod 8

      // stage chunk c (32 b-rows, one shot with 8 waves): tr/sppo sc1, img cached
      #define STG(c, buf) {                                                     \
        int br = (c) * 32 + brow0;                                              \
        float* dst = &stg[buf][(w * 4) * 64];                                   \
        gl_lds16c(trC  + (size_t)br * INQ  + icol, dst);                        \
        gl_lds16 (imgt + (size_t)br * INQ  + icol, dst + 2048);                 \
        gl_lds16c(sppo + (size_t)br * 1024 + scol, dst + 4096);                 \
      }

      STG(0, 0);
      for (int c = 0; c < 8; ++c) {
        const int buf = c & 1;
        if (c < 7) {
          STG(c + 1, buf ^ 1);
          __builtin_amdgcn_s_waitcnt(0x0F73);     // vmcnt(3): chunk c landed
        } else {
          __builtin_amdgcn_s_waitcnt(0x0F70);     // vmcnt(0)
        }
        __builtin_amdgcn_s_barrier();
        #pragma unroll
        for (int k = 0; k < 4; ++k) {
          const int r = 8 * k + w;                // this wave's b-rows
          const float4 tA = *(const float4*)&stg[buf][r * 64 + loff];
          const float4 tB = *(const float4*)&stg[buf][r * 64 + loff + 4];
          const float4 gA = *(const float4*)&stg[buf][2048 + r * 64 + loff];
          const float4 gB = *(const float4*)&stg[buf][2048 + r * 64 + loff + 4];
          const float4 sA = *(const float4*)&stg[buf][4096 + r * 64 + soff];
          const float4 sB = *(const float4*)&stg[buf][4096 + r * 64 + soff + 4];
          const float tv[8] = { tA.x, tA.y, tA.z, tA.w, tB.x, tB.y, tB.z, tB.w };
          const float gv[8] = { gA.x, gA.y, gA.z, gA.w, gB.x, gB.y, gB.z, gB.w };
          const float ap[4] = { 1e-3f * sA.x, 1e-3f * sA.z, 1e-3f * sB.x, 1e-3f * sB.z };
          const float am[4] = { 1e-3f * sA.y, 1e-3f * sA.w, 1e-3f * sB.y, 1e-3f * sB.w };
          #pragma unroll
          for (int ii = 0; ii < 8; ++ii)
            #pragma unroll
            for (int nn = 0; nn < 4; ++nn)
              a[ii][nn] = fmaf(tv[ii], ap[nn], fmaf(gv[ii], -am[nn], a[ii][nn]));
        }
        __builtin_amdgcn_s_waitcnt(0xC07F);       // lgkmcnt(0) only
        __builtin_amdgcn_s_barrier();
      }
      #undef STG

      // ---- combine 8 wave partials in two fixed-order 4-wave rounds ----
      // part[w'][k][l], k = ii*4+nn; [4][32][64] floats = 8192 <= 12288 avail.
      float* part = &stg[0][0];
      const int kbase = (tid >> 6) * 4;           // this thread's 4 k-slots
      const int lcol  = tid & 63;
      float dsum[4];

      if (w < 4) {
        #pragma unroll
        for (int ii = 0; ii < 8; ++ii)
          #pragma unroll
          for (int nn = 0; nn < 4; ++nn)
            part[(w * 32 + (ii * 4 + nn)) * 64 + l] = a[ii][nn];
      }
      __syncthreads();
      #pragma unroll
      for (int kk = 0; kk < 4; ++kk) {
        const int k = kbase + kk;
        dsum[kk] = ((part[k * 64 + lcol] + part[2048 + k * 64 + lcol])
                    + part[4096 + k * 64 + lcol]) + part[6144 + k * 64 + lcol];
      }
      __syncthreads();
      if (w >= 4) {
        #pragma unroll
        for (int ii = 0; ii < 8; ++ii)
          #pragma unroll
          for (int nn = 0; nn < 4; ++nn)
            part[((w - 4) * 32 + (ii * 4 + nn)) * 64 + l] = a[ii][nn];
      }
      __syncthreads();
      #pragma unroll
      for (int kk = 0; kk < 4; ++kk) {
        const int k = kbase + kk;
        dsum[kk] += ((part[k * 64 + lcol] + part[2048 + k * 64 + lcol])
                     + part[4096 + k * 64 + lcol]) + part[6144 + k * 64 + lcol];
      }

      // ---- coherent Wt RMW: 1 i x 4 n per thread ----
      const int iO = ib0 + (lcol >> 3) * 8 + (tid >> 6);
      const int nO = nb0 + (lcol & 7) * 4;
      if (nO < NOUT && iO < INQ) {
        float* wp = Wt + (size_t)iO * NP + nO;
        float2 w2 = ld_coh2(wp);
        w2.x = clip01(w2.x + dsum[0]);
        w2.y = clip01(w2.y + dsum[1]);
        st_coh2(wp, w2);
        float2 w3 = ld_coh2(wp + 2);
        w3.x = clip01(w3.x + dsum[2]);
        w3.y = clip01(w3.y + dsum[3]);
        st_coh2(wp + 2, w3);
      }
    }

    // ---- all blocks: trace recurrence + next list (own row), in P2 epoch ---
    {
      const float* imrow = img + (size_t)t * IMSZ + (size_t)blk * INQ;
      const float* trCrow = trC + (size_t)blk * INQ;
      float* trNrow = trN + (size_t)blk * INQ;
      for (int i = tid * 2; i < INQ; i += 2 * NTHR) {
        float2 o = ld_coh2(trCrow + i);
        float2 iv = *(const float2*)(imrow + i);
        st_coh2(trNrow + i, make_float2(fmaf(0.9f, o.x, iv.x),
                                        fmaf(0.9f, o.y, iv.y)));
      }
    }
    if (t + 1 < T_STEPS) build_list(t + 1, (t + 1) & 1);

    ++bt; gbar(bar, bt, blk);
  }

  // ---- final: W_out[n][i] = Wt[i][n] ----
  for (int e = blk * NTHR + tid; e < NOUT * INQ; e += GRID * NTHR) {
    int n = e / INQ, i = e % INQ;
    Wout[e] = ld_coh(Wt + (size_t)i * NP + n);
  }
}

extern "C" void kernel_launch(void* const* d_in, const int* in_sizes, int n_in,
                              void* d_out, int out_size, void* d_ws, size_t ws_size,
                              hipStream_t stream) {
  const float* img = (const float*)d_in[0];
  const float* W   = (const float*)d_in[1];
  float* out = (float*)d_out;
  float* ws  = (float*)d_ws;

  hipMemsetAsync(d_ws, 0, (size_t)WS_FLOATS * sizeof(float), stream);

  void* args[] = { (void*)&img, (void*)&W, (void*)&out, (void*)&ws };
  hipLaunchCooperativeKernel((const void*)snn_kernel, dim3(GRID), dim3(NTHR),
                             args, 0, stream);
}